// Round 10
// baseline (76.991 us; speedup 1.0000x reference)
//
#include <hip/hip_runtime.h>
#include <math.h>

// Problem constants (reference: pos [64,1024,3] fp32, rad=0.15)
#define TN     64
#define NP     1024
#define RADIUS 0.15f
#define MIN_D  (2.0f * RADIUS)
#define R2     (MIN_D * MIN_D)

#define SPLIT  16                  // blocks per timestep -> 1024 blocks
#define GI     8                   // i-rows per group: SMALL tile -> ~45 live VGPRs, no spill
#define NGRP   (NP / GI)           // 128 groups per timestep
#define GPB    (NGRP / SPLIT)      // 8 groups per block
#define BLOCK  256
#define NBLK   (TN * SPLIT)        // 1024 blocks

// R10 theory: R4-R9 all paired a 48-float pinned tile with 16(x2)-deep unrolled
// bodies -> peak register pressure at/over the 128-VGPR cap -> scratch spills /
// pressure serialization, a ~constant ~20 us tax that made every inner-loop
// rewrite look neutral. This version keeps the working set tiny (24 pinned
// floats, no unroll-2) so spilling is impossible, while keeping the branchless
// 12-inst pair body and b128 LDS j-reads.
__launch_bounds__(BLOCK, 4)
__global__ void collide_kernel(const float* __restrict__ pos,
                               float* __restrict__ partial) {
    __shared__ float4 shp[NP];     // x,y,z,pad: one ds_read_b128 per j, conflict-free
    const int bid   = blockIdx.x;
    const int t     = bid / SPLIT;
    const int split = bid % SPLIT;
    const int tid   = threadIdx.x;

    // stage + repack: thread u reads 3 float4 (points 4u..4u+3), writes 4 padded
    {
        const float4* p4 = (const float4*)(pos + (size_t)t * NP * 3);
        const float4 a = p4[3 * tid + 0];
        const float4 b = p4[3 * tid + 1];
        const float4 c = p4[3 * tid + 2];
        shp[4 * tid + 0] = make_float4(a.x, a.y, a.z, 0.0f);
        shp[4 * tid + 1] = make_float4(a.w, b.x, b.y, 0.0f);
        shp[4 * tid + 2] = make_float4(b.z, b.w, c.x, 0.0f);
        shp[4 * tid + 3] = make_float4(c.y, c.z, c.w, 0.0f);
    }
    __syncthreads();

    unsigned int cnt = 0;
    float loss = 0.0f;

    #pragma unroll 1               // one group's 24 pins live at a time
    for (int m = 0; m < GPB; ++m) {
        // snake: per-block total tail length constant (sum g = 508 for all split)
        const int g = (m & 1) ? (m * SPLIT + (SPLIT - 1 - split))
                              : (m * SPLIT + split);
        const int b = g * GI;

        float xi[GI], yi[GI], zi[GI];
        #pragma unroll
        for (int k = 0; k < GI; ++k) {
            const float4 pk = shp[b + k];   // wave-uniform -> LDS broadcast
            xi[k] = pk.x; yi[k] = pk.y; zi[k] = pk.z;
        }
        // pin tile in VGPRs (blocks LDS remat; R2 evidence: VGPR=32, 56 ops/pair)
        #pragma unroll
        for (int k = 0; k < GI; ++k)
            asm volatile("" : "+v"(xi[k]), "+v"(yi[k]), "+v"(zi[k]));

        // head: in-group pairs, one lane per j (tiny, once/group)
        if (tid < GI - 1) {
            const float4 pj = shp[b + 1 + tid];
            #pragma unroll
            for (int k = 0; k < GI; ++k) {
                if (k <= tid) {                        // i = b+k < j = b+1+tid
                    const float dx = xi[k] - pj.x;
                    const float dy = yi[k] - pj.y;
                    const float dz = zi[k] - pj.z;
                    const float d2 = dx * dx + dy * dy + dz * dz;
                    cnt += (d2 < R2) ? 1u : 0u;
                    const float pen = fmaxf(MIN_D - __builtin_amdgcn_sqrtf(d2), 0.0f);
                    loss += pen * pen;
                }
            }
        }

        // tail: branchless, one b128 read + 8 x 12 VALU insts per j
        for (int j = b + GI + tid; j < NP; j += BLOCK) {
            const float4 pj = shp[j];
            #pragma unroll
            for (int k = 0; k < GI; ++k) {
                const float dx = xi[k] - pj.x;
                const float dy = yi[k] - pj.y;
                const float dz = zi[k] - pj.z;
                const float d2 = dx * dx + dy * dy + dz * dz;
                cnt += (d2 < R2) ? 1u : 0u;            // v_cmp + v_addc (vcc only)
                const float pen = fmaxf(MIN_D - __builtin_amdgcn_sqrtf(d2), 0.0f);
                loss += pen * pen;                     // exact 0 for non-hits
            }
        }
    }

    // wave reduction, then cross-wave via LDS
    float fcnt = (float)cnt;
    #pragma unroll
    for (int off = 32; off > 0; off >>= 1) {
        fcnt += __shfl_down(fcnt, off);
        loss += __shfl_down(loss, off);
    }
    __shared__ float cs[BLOCK / 64], ls[BLOCK / 64];
    const int wave = tid >> 6;
    if ((tid & 63) == 0) { cs[wave] = fcnt; ls[wave] = loss; }
    __syncthreads();
    if (tid == 0) {
        float c = 0.0f, l = 0.0f;
        #pragma unroll
        for (int w = 0; w < BLOCK / 64; ++w) { c += cs[w]; l += ls[w]; }
        partial[2 * bid + 0] = c;   // unconditional store: no init kernel needed
        partial[2 * bid + 1] = l;
    }
}

__global__ void finalize_kernel(const float* __restrict__ partial,
                                float* __restrict__ out) {
    const int tid = threadIdx.x;
    float c = 0.0f, l = 0.0f;
    #pragma unroll
    for (int i = 0; i < NBLK / BLOCK; ++i) {           // 4 float2 per thread
        const float2 p = ((const float2*)partial)[tid + i * BLOCK];
        c += p.x;
        l += p.y;
    }
    #pragma unroll
    for (int off = 32; off > 0; off >>= 1) {
        c += __shfl_down(c, off);
        l += __shfl_down(l, off);
    }
    __shared__ float cs[BLOCK / 64], ls[BLOCK / 64];
    const int wave = tid >> 6;
    if ((tid & 63) == 0) { cs[wave] = c; ls[wave] = l; }
    __syncthreads();
    if (tid == 0) {
        float ct = 0.0f, lt = 0.0f;
        #pragma unroll
        for (int w = 0; w < BLOCK / 64; ++w) { ct += cs[w]; lt += ls[w]; }
        out[0] = ct;   // harness reads d_out as float32; count exact (< 2^24)
        out[1] = lt;
    }
}

extern "C" void kernel_launch(void* const* d_in, const int* in_sizes, int n_in,
                              void* d_out, int out_size, void* d_ws, size_t ws_size,
                              hipStream_t stream) {
    const float* pos     = (const float*)d_in[0];
    float*       partial = (float*)d_ws;
    float*       out     = (float*)d_out;

    collide_kernel<<<NBLK, BLOCK, 0, stream>>>(pos, partial);
    finalize_kernel<<<1, BLOCK, 0, stream>>>(partial, out);
}